// Round 1
// baseline (145.607 us; speedup 1.0000x reference)
//
#include <hip/hip_runtime.h>

// x: (B, T+1, T) fp32.  pad = x[:,0,:], sig = x[:,1:,:]
// s[t] = sum_i |sig[i,t]|; w = sigmoid(pad - s)
// out[:,0,:] = w*pad; out[:,1+i,:] = (1-w[i])*sig[i,:]
//
// Block (b, stripe) owns columns [c0,c0+COLS): computes their colsums -> w,
// then scales+writes output ROWS [c0,c0+COLS) (scale of row i is 1-w[i]).

#define TDIM 2048
#define BDIM 16
#define COLS 32          // columns (== output rows) per block
#define NTHREADS 256

__global__ __launch_bounds__(NTHREADS) void pb_kernel(const float* __restrict__ x,
                                                      float* __restrict__ out) {
    const int blk    = blockIdx.x;                 // 0 .. B*(T/COLS)-1
    const int b      = blk / (TDIM / COLS);
    const int stripe = blk % (TDIM / COLS);
    const int c0     = stripe * COLS;
    const int t      = threadIdx.x;

    const size_t planeStride = (size_t)(TDIM + 1) * TDIM;
    const float* xb  = x   + (size_t)b * planeStride;   // batch base
    float*       ob  = out + (size_t)b * planeStride;
    const float* sig = xb + TDIM;                       // rows 1..T of x

    // ---- Phase 1: column sums for columns [c0, c0+COLS) ----
    // 8 lanes per row (each lane loads a float4 = 4 columns), 32 rows/iter.
    const int li = t & 7;          // lane-in-row: 0..7
    const int g  = t >> 3;         // row group:   0..31
    const int colbase = c0 + 4 * li;

    float a0 = 0.f, a1 = 0.f, a2 = 0.f, a3 = 0.f;
    for (int r = g; r < TDIM; r += 32) {
        const float4 v = *reinterpret_cast<const float4*>(sig + (size_t)r * TDIM + colbase);
        a0 += fabsf(v.x); a1 += fabsf(v.y); a2 += fabsf(v.z); a3 += fabsf(v.w);
    }

    __shared__ float lds_p[32][COLS];   // [row-group][column] partials, 4 KB
    lds_p[g][4 * li + 0] = a0;
    lds_p[g][4 * li + 1] = a1;
    lds_p[g][4 * li + 2] = a2;
    lds_p[g][4 * li + 3] = a3;

    __shared__ float lds_scale[COLS];
    __syncthreads();

    if (t < COLS) {
        float s = 0.f;
        #pragma unroll
        for (int gg = 0; gg < 32; ++gg) s += lds_p[gg][t];
        const float p = xb[c0 + t];                     // pad element
        const float w = 1.0f / (1.0f + expf(s - p));    // sigmoid(p - s)
        ob[c0 + t]    = w * p;                          // out row 0
        lds_scale[t]  = 1.0f - w;
    }
    __syncthreads();

    // ---- Phase 2: output rows [c0, c0+COLS): out[1+r][*] = scale[r]*sig[r][*] ----
    for (int r = 0; r < COLS; ++r) {
        const float  sc     = lds_scale[r];
        const size_t rowoff = (size_t)(c0 + r) * TDIM;
        const float4* src = reinterpret_cast<const float4*>(sig + rowoff);
        float4*       dst = reinterpret_cast<float4*>(ob + TDIM + rowoff);
        #pragma unroll
        for (int k = 0; k < (TDIM / 4) / NTHREADS; ++k) {   // 2 iters
            float4 v = src[t + k * NTHREADS];
            v.x *= sc; v.y *= sc; v.z *= sc; v.w *= sc;
            dst[t + k * NTHREADS] = v;
        }
    }
}

extern "C" void kernel_launch(void* const* d_in, const int* in_sizes, int n_in,
                              void* d_out, int out_size, void* d_ws, size_t ws_size,
                              hipStream_t stream) {
    const float* x   = (const float*)d_in[0];
    float*       out = (float*)d_out;
    const int nblocks = BDIM * (TDIM / COLS);   // 16 * 64 = 1024
    pb_kernel<<<nblocks, NTHREADS, 0, stream>>>(x, out);
}

// Round 3
// 121.682 us; speedup vs baseline: 1.1966x; 1.1966x over previous
//
#include <hip/hip_runtime.h>

// x: (B, T+1, T) fp32.  pad = x[:,0,:], sig = x[:,1:,:]
// s[t] = sum_i |sig[i,t]|; w = sigmoid(pad - s)
// out[:,0,:] = w*pad; out[:,1+i,:] = (1-w[i])*sig[i,:]
//
// Block (b, stripe) owns columns [c0,c0+COLS): computes their colsums -> w,
// then scales+writes output ROWS [c0,c0+COLS) (scale of row i is 1-w[i]).
//
// 512 threads/block: 8 waves * 4 blocks/CU = 32 waves/CU (max occupancy).

#define TDIM 2048
#define BDIM 16
#define COLS 32          // columns (== output rows) per block
#define NTHREADS 512

typedef float floatx4 __attribute__((ext_vector_type(4)));

__global__ __launch_bounds__(NTHREADS, 8) void pb_kernel(const float* __restrict__ x,
                                                         float* __restrict__ out) {
    const int blk    = blockIdx.x;                 // 0 .. B*(T/COLS)-1
    const int b      = blk / (TDIM / COLS);
    const int stripe = blk % (TDIM / COLS);
    const int c0     = stripe * COLS;
    const int t      = threadIdx.x;

    const size_t planeStride = (size_t)(TDIM + 1) * TDIM;
    const float* xb  = x   + (size_t)b * planeStride;   // batch base
    float*       ob  = out + (size_t)b * planeStride;
    const float* sig = xb + TDIM;                       // rows 1..T of x

    // ---- Phase 1: column sums for columns [c0, c0+COLS) ----
    // 8 lanes per row (each lane loads a float4 = 4 columns), 64 rows/iter.
    const int li = t & 7;          // lane-in-row: 0..7
    const int g  = t >> 3;         // row group:   0..63
    const int colbase = c0 + 4 * li;

    float a0 = 0.f, a1 = 0.f, a2 = 0.f, a3 = 0.f;
    for (int r = g; r < TDIM; r += 64) {               // 32 iterations
        const floatx4 v = *reinterpret_cast<const floatx4*>(sig + (size_t)r * TDIM + colbase);
        a0 += fabsf(v.x); a1 += fabsf(v.y); a2 += fabsf(v.z); a3 += fabsf(v.w);
    }

    __shared__ float lds_p[64][COLS];   // [row-group][column] partials, 8 KB
    lds_p[g][4 * li + 0] = a0;
    lds_p[g][4 * li + 1] = a1;
    lds_p[g][4 * li + 2] = a2;
    lds_p[g][4 * li + 3] = a3;

    __shared__ float lds_scale[COLS];
    __syncthreads();

    if (t < COLS) {
        float s = 0.f;
        #pragma unroll
        for (int gg = 0; gg < 64; ++gg) s += lds_p[gg][t];
        const float p = xb[c0 + t];                     // pad element
        const float w = 1.0f / (1.0f + expf(s - p));    // sigmoid(p - s)
        ob[c0 + t]    = w * p;                          // out row 0
        lds_scale[t]  = 1.0f - w;
    }
    __syncthreads();

    // ---- Phase 2: output rows [c0, c0+COLS): out[1+r][*] = scale[r]*sig[r][*] ----
    // 512 threads * float4 = one full 2048-float row per iteration.
    for (int r = 0; r < COLS; ++r) {
        const float  sc     = lds_scale[r];
        const size_t rowoff = (size_t)(c0 + r) * TDIM;
        const floatx4* src = reinterpret_cast<const floatx4*>(sig + rowoff);
        floatx4*       dst = reinterpret_cast<floatx4*>(ob + TDIM + rowoff);
        floatx4 v = src[t];
        v.x *= sc; v.y *= sc; v.z *= sc; v.w *= sc;
        __builtin_nontemporal_store(v, dst + t);       // output never re-read
    }
}

extern "C" void kernel_launch(void* const* d_in, const int* in_sizes, int n_in,
                              void* d_out, int out_size, void* d_ws, size_t ws_size,
                              hipStream_t stream) {
    const float* x   = (const float*)d_in[0];
    float*       out = (float*)d_out;
    const int nblocks = BDIM * (TDIM / COLS);   // 16 * 64 = 1024
    pb_kernel<<<nblocks, NTHREADS, 0, stream>>>(x, out);
}